// Round 5
// baseline (992.053 us; speedup 1.0000x reference)
//
#include <hip/hip_runtime.h>

#define NEGF (-1e30f)

// Problem constants (from setup_inputs: B=8, T=128, U=64, V=1024)
#define B_   8
#define T_   128
#define U_   64
#define U1_  65
#define V_   1024
#define PAD_ 66                 // padded row stride for lpb/lpl
#define ROWS_ (B_*T_*U1_)       // 66560
#define WS_PER_ (T_*PAD_)       // 8448 floats per batch per array
#define K1_SUB_   (ROWS_/4)     // 16640 blocks per pass (R2 geometry)
#define K1_PASSES_ 4            // DIAGNOSTIC: 4 idempotent passes in one dispatch
#define REP_       32           // DIAGNOSTIC: DP repetitions inside k2

typedef float f32x4 __attribute__((ext_vector_type(4)));

// lane l receives lane l-1's value; lane 0 keeps its own (DPP wave_shr:1).
__device__ __forceinline__ float wave_shr1(float x) {
  return __int_as_float(__builtin_amdgcn_update_dpp(
      __float_as_int(x), __float_as_int(x), 0x138, 0xf, 0xf, 0));
}

// ---------------------------------------------------------------------------
// K1: R2's wave-per-row log-softmax, replicated K1_PASSES_ times in ONE
//     dispatch (idempotent identical writes) so its counters surface in the
//     rocprof top-5. k1_true = dur / K1_PASSES_.
// ---------------------------------------------------------------------------
__global__ __launch_bounds__(256) void k1_logsoftmax(
    const float* __restrict__ acts, const int* __restrict__ labels,
    const int* __restrict__ label_lens,
    float* __restrict__ lpb, float* __restrict__ lpl, int* __restrict__ cnt) {
  const int lane = threadIdx.x & 63;
  const int wv   = threadIdx.x >> 6;
  const int sub  = (int)(blockIdx.x % K1_SUB_);    // pass-local block id
  const int row  = sub * 4 + wv;

  if (blockIdx.x == 0 && threadIdx.x == 0) *cnt = 0;   // k2's completion counter

  const int b   = row / (T_ * U1_);
  const int rem = row - b * (T_ * U1_);
  const int t   = rem / U1_;
  const int u   = rem - t * U1_;

  const float* __restrict__ p = acts + (size_t)row * V_;

  // hoisted label-path loads (lane 0 only); overlap with row load + reductions
  int ll_ = 0; float labv = 0.0f;
  if (lane == 0 && u < U_) {
    ll_  = label_lens[b];
    labv = p[labels[b * U_ + u]];                  // in [1, V)
  }

  f32x4 v0 = *(const f32x4*)(p +   0 + lane * 4);
  f32x4 v1 = *(const f32x4*)(p + 256 + lane * 4);
  f32x4 v2 = *(const f32x4*)(p + 512 + lane * 4);
  f32x4 v3 = *(const f32x4*)(p + 768 + lane * 4);

  float m = fmaxf(fmaxf(fmaxf(v0.x, v0.y), fmaxf(v0.z, v0.w)),
            fmaxf(fmaxf(fmaxf(v1.x, v1.y), fmaxf(v1.z, v1.w)),
            fmaxf(fmaxf(fmaxf(v2.x, v2.y), fmaxf(v2.z, v2.w)),
                  fmaxf(fmaxf(v3.x, v3.y), fmaxf(v3.z, v3.w)))));
  #pragma unroll
  for (int o = 32; o; o >>= 1) m = fmaxf(m, __shfl_xor(m, o, 64));

  float s = __expf(v0.x - m) + __expf(v0.y - m) + __expf(v0.z - m) + __expf(v0.w - m)
          + __expf(v1.x - m) + __expf(v1.y - m) + __expf(v1.z - m) + __expf(v1.w - m)
          + __expf(v2.x - m) + __expf(v2.y - m) + __expf(v2.z - m) + __expf(v2.w - m)
          + __expf(v3.x - m) + __expf(v3.y - m) + __expf(v3.z - m) + __expf(v3.w - m);
  #pragma unroll
  for (int o = 32; o; o >>= 1) s += __shfl_xor(s, o, 64);

  float lse = m + __logf(s);                       // s >= 1

  if (lane == 0) {
    int base = (b * T_ + t) * PAD_;
    lpb[base + u] = v0.x - lse;                    // element 0 lives in lane 0's v0.x
    if (u < U_) lpl[base + u] = (u < ll_) ? (labv - lse) : NEGF;
  }
}

// ---------------------------------------------------------------------------
// K2: R2's anti-diagonal DP, with the prefix+DP+cost section repeated REP_
//     times (idempotent; asm keep-alives defeat LICM) so the DP cost
//     surfaces in top-5. k2_dp_true ≈ (dur - staging) / REP_.
// ---------------------------------------------------------------------------
__global__ __launch_bounds__(256) void k2_alpha(
    const float* __restrict__ lpb, const float* __restrict__ lpl,
    const int* __restrict__ act_lens, const int* __restrict__ label_lens,
    float* __restrict__ costs, int* __restrict__ cnt, float* __restrict__ out) {
  __shared__ float lpb_s[WS_PER_];
  __shared__ float lpl_s[WS_PER_];
  __shared__ float alpha0_s[T_];
  const int b = blockIdx.x;

  {  // flat float4 copy (WS_PER_ multiple of 4; batch base is 16B aligned)
    const f32x4* s1 = (const f32x4*)(lpb + (size_t)b * WS_PER_);
    const f32x4* s2 = (const f32x4*)(lpl + (size_t)b * WS_PER_);
    f32x4* d1 = (f32x4*)lpb_s;
    f32x4* d2 = (f32x4*)lpl_s;
    #pragma unroll
    for (int k = 0; k < 9; ++k) {                  // 9*256 >= 2112
      int i = k * 256 + (int)threadIdx.x;
      if (i < WS_PER_ / 4) { d1[i] = s1[i]; d2[i] = s2[i]; }
    }
  }
  __syncthreads();
  if (threadIdx.x >= 64) return;

  const int l  = threadIdx.x;
  const int tl = act_lens[b] - 1;
  const int ll = label_lens[b];

  #pragma unroll 1
  for (int rep = 0; rep < REP_; ++rep) {
    // alpha[t][0] = sum_{j<t} lpb[j][0] (exclusive prefix over T=128)
    float x0 = lpb_s[l * PAD_];
    float x1 = lpb_s[(l + 64) * PAD_];
    asm volatile("" : "+v"(x0), "+v"(x1));         // defeat LICM across reps
    float s0 = x0;
    #pragma unroll
    for (int o = 1; o < 64; o <<= 1) { float tmp = __shfl_up(s0, o, 64); if (l >= o) s0 += tmp; }
    float tot0 = __shfl(s0, 63, 64);
    float s1v = x1;
    #pragma unroll
    for (int o = 1; o < 64; o <<= 1) { float tmp = __shfl_up(s1v, o, 64); if (l >= o) s1v += tmp; }
    alpha0_s[l]      = s0 - x0;
    alpha0_s[l + 64] = tot0 + s1v - x1;

    // diagonal sweep: at diagonal d, lane l computes cell (t = d-u, u = l+1)
    const int u = l + 1;
    float a    = NEGF;
    asm volatile("" : "+v"(a));                    // force per-rep recompute
    float fin  = 0.0f;
    bool  have = false;

    int   tc1 = min(max(1 - u, 0), T_ - 1);
    int   tm1 = max(tc1 - 1, 0);
    float pb  = lpb_s[tm1 * PAD_ + u];
    float pl  = lpl_s[tc1 * PAD_ + (u - 1)];
    float pa0 = alpha0_s[tc1];

    for (int d = 1; d <= T_ - 1 + U_; ++d) {
      int   tcn = min(max(d + 1 - u, 0), T_ - 1);
      int   tmn = max(tcn - 1, 0);
      float nb  = lpb_s[tmn * PAD_ + u];
      float nl  = lpl_s[tcn * PAD_ + (u - 1)];
      float na0 = alpha0_s[tcn];

      int  t     = d - u;
      bool valid = (t >= 0) && (t < T_);
      float left = wave_shr1(a);                   // alpha[t][u-1] from lane l-1
      if (l == 0) left = pa0;                      // u-1 == 0 column
      float blank = (t >= 1 && t < T_) ? (a + pb) : NEGF;
      float label = left + pl;
      float mm = fmaxf(blank, label);
      float dd = fminf(blank, label) - mm;         // <= 0; exp underflows safely
      float anew = mm + __logf(1.0f + __expf(dd));
      a = valid ? anew : NEGF;
      if (valid && t == tl && u == ll) { fin = a; have = true; }

      pb = nb; pl = nl; pa0 = na0;
    }
    if (have)              costs[b] = -(fin + lpb_s[tl * PAD_ + ll]);
    if (l == 0 && ll == 0) costs[b] = -(alpha0_s[tl] + lpb_s[tl * PAD_]);
  }

  // last block to arrive sums the 8 costs (deterministic: single writer)
  __threadfence();
  if (l == 0) {
    int old = atomicAdd(cnt, 1);
    if (old == B_ - 1) {
      __threadfence();
      volatile const float* vc = costs;
      float s = 0.0f;
      #pragma unroll
      for (int i = 0; i < B_; ++i) s += vc[i];
      out[0] = s;
    }
  }
}

extern "C" void kernel_launch(void* const* d_in, const int* in_sizes, int n_in,
                              void* d_out, int out_size, void* d_ws, size_t ws_size,
                              hipStream_t stream) {
  const float* acts       = (const float*)d_in[0];
  const int*   labels     = (const int*)d_in[1];
  const int*   act_lens   = (const int*)d_in[2];
  const int*   label_lens = (const int*)d_in[3];

  float* lpb   = (float*)d_ws;                       // B*T*PAD floats
  float* lpl   = lpb + (size_t)B_ * WS_PER_;         // B*T*PAD floats
  float* costs = lpl + (size_t)B_ * WS_PER_;         // B floats
  int*   cnt   = (int*)(costs + B_);                 // 1 int

  k1_logsoftmax<<<K1_SUB_ * K1_PASSES_, 256, 0, stream>>>(acts, labels, label_lens, lpb, lpl, cnt);
  k2_alpha<<<B_, 256, 0, stream>>>(lpb, lpl, act_lens, label_lens, costs, cnt, (float*)d_out);
}

// Round 6
// 66.737 us; speedup vs baseline: 14.8652x; 14.8652x over previous
//
#include <hip/hip_runtime.h>

#define NEGF (-1e30f)
#define INV_LN2 1.4426950408889634f
#define LN2F    0.6931471805599453f

// Problem constants (from setup_inputs: B=8, T=128, U=64, V=1024)
#define B_   8
#define T_   128
#define U_   64
#define U1_  65
#define V_   1024
#define PAD_ 66                 // padded row stride for lpb/lpl
#define ROWS_ (B_*T_*U1_)       // 66560
#define WS_PER_ (T_*PAD_)       // 8448 floats per batch per array

typedef float f32x4 __attribute__((ext_vector_type(4)));

// lane l receives lane l-1's value; lane 0 keeps its own (DPP wave_shr:1).
__device__ __forceinline__ float wave_shr1(float x) {
  return __int_as_float(__builtin_amdgcn_update_dpp(
      __float_as_int(x), __float_as_int(x), 0x138, 0xf, 0xf, 0));
}

// ---------------------------------------------------------------------------
// K1: R2's wave-per-row log-softmax (known-good geometry), but emits values
//     in LOG2 domain: (x - lse) * log2(e). k2 then uses raw v_exp/v_log.
// ---------------------------------------------------------------------------
__global__ __launch_bounds__(256) void k1_logsoftmax(
    const float* __restrict__ acts, const int* __restrict__ labels,
    const int* __restrict__ label_lens,
    float* __restrict__ lpb, float* __restrict__ lpl, int* __restrict__ cnt) {
  const int lane = threadIdx.x & 63;
  const int wv   = threadIdx.x >> 6;
  const int row  = blockIdx.x * 4 + wv;

  if (blockIdx.x == 0 && threadIdx.x == 0) *cnt = 0;   // k2's completion counter

  const int b   = row / (T_ * U1_);
  const int rem = row - b * (T_ * U1_);
  const int t   = rem / U1_;
  const int u   = rem - t * U1_;

  const float* __restrict__ p = acts + (size_t)row * V_;

  // hoisted label-path loads (lane 0 only); overlap with row load + reductions
  int ll_ = 0; float labv = 0.0f;
  if (lane == 0 && u < U_) {
    ll_  = label_lens[b];
    labv = p[labels[b * U_ + u]];                  // in [1, V)
  }

  f32x4 v0 = *(const f32x4*)(p +   0 + lane * 4);
  f32x4 v1 = *(const f32x4*)(p + 256 + lane * 4);
  f32x4 v2 = *(const f32x4*)(p + 512 + lane * 4);
  f32x4 v3 = *(const f32x4*)(p + 768 + lane * 4);

  float m = fmaxf(fmaxf(fmaxf(v0.x, v0.y), fmaxf(v0.z, v0.w)),
            fmaxf(fmaxf(fmaxf(v1.x, v1.y), fmaxf(v1.z, v1.w)),
            fmaxf(fmaxf(fmaxf(v2.x, v2.y), fmaxf(v2.z, v2.w)),
                  fmaxf(fmaxf(v3.x, v3.y), fmaxf(v3.z, v3.w)))));
  #pragma unroll
  for (int o = 32; o; o >>= 1) m = fmaxf(m, __shfl_xor(m, o, 64));

  float s = __expf(v0.x - m) + __expf(v0.y - m) + __expf(v0.z - m) + __expf(v0.w - m)
          + __expf(v1.x - m) + __expf(v1.y - m) + __expf(v1.z - m) + __expf(v1.w - m)
          + __expf(v2.x - m) + __expf(v2.y - m) + __expf(v2.z - m) + __expf(v2.w - m)
          + __expf(v3.x - m) + __expf(v3.y - m) + __expf(v3.z - m) + __expf(v3.w - m);
  #pragma unroll
  for (int o = 32; o; o >>= 1) s += __shfl_xor(s, o, 64);

  float lse = m + __logf(s);                       // s >= 1

  if (lane == 0) {
    int base = (b * T_ + t) * PAD_;
    lpb[base + u] = (v0.x - lse) * INV_LN2;        // log2 domain
    if (u < U_) lpl[base + u] = (u < ll_) ? ((labv - lse) * INV_LN2) : NEGF;
  }
}

// ---------------------------------------------------------------------------
// K2: anti-diagonal DP in log2 domain. Depth-2 prefetch with pointer-
//     increment addressing (no mul/clamp on the issue path; OOB indices stay
//     inside our static LDS and the results are masked). Raw v_exp/v_log.
// ---------------------------------------------------------------------------
__global__ __launch_bounds__(256) void k2_alpha(
    const float* __restrict__ lpb, const float* __restrict__ lpl,
    const int* __restrict__ act_lens, const int* __restrict__ label_lens,
    float* __restrict__ costs, int* __restrict__ cnt, float* __restrict__ out) {
  __shared__ float lpb_s[WS_PER_];
  __shared__ float lpl_s[WS_PER_];   // contiguous after lpb_s: deep-lane overrun lands here (masked)
  __shared__ float alpha0_s[256];    // padded: issue index runs to ~195
  const int b = blockIdx.x;

  {  // flat float4 copy (WS_PER_ multiple of 4; batch base is 16B aligned)
    const f32x4* s1 = (const f32x4*)(lpb + (size_t)b * WS_PER_);
    const f32x4* s2 = (const f32x4*)(lpl + (size_t)b * WS_PER_);
    f32x4* d1 = (f32x4*)lpb_s;
    f32x4* d2 = (f32x4*)lpl_s;
    #pragma unroll
    for (int k = 0; k < 9; ++k) {                  // 9*256 >= 2112
      int i = k * 256 + (int)threadIdx.x;
      if (i < WS_PER_ / 4) { d1[i] = s1[i]; d2[i] = s2[i]; }
    }
  }
  __syncthreads();
  if (threadIdx.x >= 64) return;

  const int l  = threadIdx.x;
  const int tl = act_lens[b] - 1;
  const int ll = label_lens[b];

  // alpha[t][0] = sum_{j<t} lpb2[j][0]  (exclusive prefix over T=128)
  float x0 = lpb_s[l * PAD_];
  float x1 = lpb_s[(l + 64) * PAD_];
  float s0 = x0;
  #pragma unroll
  for (int o = 1; o < 64; o <<= 1) { float tmp = __shfl_up(s0, o, 64); if (l >= o) s0 += tmp; }
  float tot0 = __shfl(s0, 63, 64);
  float s1v = x1;
  #pragma unroll
  for (int o = 1; o < 64; o <<= 1) { float tmp = __shfl_up(s1v, o, 64); if (l >= o) s1v += tmp; }
  alpha0_s[l]      = s0 - x0;
  alpha0_s[l + 64] = tot0 + s1v - x1;
  // pad the tail so deep issue indices read harmless finite values
  alpha0_s[128 + l] = NEGF;
  if (l < 64) alpha0_s[192 + l] = NEGF;

  const int u    = l + 1;
  const bool isme = (u == ll);
  float a    = NEGF;
  float fin  = 0.0f;
  bool  have = false;

  // issue-side indices: pb(dc)=lpb_s[max(dc-u-1,0)*PAD+u], pl(dc)=lpl_s[max(dc-u,0)*PAD+(u-1)],
  // pa0(dc)=alpha0_s[dc-1]. Advance by conditional +PAD (no mul/clamp per iter).
  int ipb = u;
  int ipl = u - 1;
  int ia0 = 0;

  // prefetch for dc = 1
  float pb0 = lpb_s[ipb], pl0 = lpl_s[ipl], pa00 = alpha0_s[ia0];
  ipb += (1 > u)  ? PAD_ : 0;
  ipl += (1 >= u) ? PAD_ : 0;
  ia0  = 1;
  // prefetch for dc = 2
  float pb1 = lpb_s[ipb], pl1 = lpl_s[ipl], pa01 = alpha0_s[ia0];
  ipb += (2 > u)  ? PAD_ : 0;
  ipl += (2 >= u) ? PAD_ : 0;
  ia0  = 2;

#define STEP_(DD, PB, PL, PA0) do {                                   \
    int  t_ = (DD) - u;                                               \
    float left = wave_shr1(a);                                        \
    if (l == 0) left = (PA0);                                         \
    float blank = a + (PB);        /* a==NEGF while inactive/t==0 */  \
    float label = left + (PL);                                        \
    float mx = fmaxf(blank, label);                                   \
    float mn = fminf(blank, label);                                   \
    float e_; asm("v_exp_f32 %0, %1" : "=v"(e_) : "v"(mn - mx));      \
    float g_; asm("v_log_f32 %0, %1" : "=v"(g_) : "v"(1.0f + e_));    \
    float anew = mx + g_;                                             \
    bool valid = (t_ >= 0) && (t_ < T_);                              \
    a = valid ? anew : NEGF;                                          \
    if (isme && t_ == tl) { fin = a; have = true; }                   \
  } while (0)

  #pragma unroll 1
  for (int d = 1; d <= T_ - 1 + U_; d += 2) {      // d = 1,3,...,191 (step d+1=192 is all-invalid)
    // issue for dc = d+2
    float nb0 = lpb_s[ipb], nl0 = lpl_s[ipl], na00 = alpha0_s[ia0];
    ipb += (d + 2 > u)  ? PAD_ : 0;
    ipl += (d + 2 >= u) ? PAD_ : 0;
    ++ia0;
    STEP_(d, pb0, pl0, pa00);
    // issue for dc = d+3
    float nb1 = lpb_s[ipb], nl1 = lpl_s[ipl], na01 = alpha0_s[ia0];
    ipb += (d + 3 > u)  ? PAD_ : 0;
    ipl += (d + 3 >= u) ? PAD_ : 0;
    ++ia0;
    STEP_(d + 1, pb1, pl1, pa01);

    pb0 = nb0; pl0 = nl0; pa00 = na00;
    pb1 = nb1; pl1 = nl1; pa01 = na01;
  }
#undef STEP_

  if (have)              costs[b] = -(fin + lpb_s[tl * PAD_ + ll]) * LN2F;
  if (l == 0 && ll == 0) costs[b] = -(alpha0_s[tl] + lpb_s[tl * PAD_]) * LN2F;

  // last block to arrive sums the 8 costs (deterministic: single writer)
  __threadfence();
  if (l == 0) {
    int old = atomicAdd(cnt, 1);
    if (old == B_ - 1) {
      __threadfence();
      volatile const float* vc = costs;
      float s = 0.0f;
      #pragma unroll
      for (int i = 0; i < B_; ++i) s += vc[i];
      out[0] = s;
    }
  }
}

extern "C" void kernel_launch(void* const* d_in, const int* in_sizes, int n_in,
                              void* d_out, int out_size, void* d_ws, size_t ws_size,
                              hipStream_t stream) {
  const float* acts       = (const float*)d_in[0];
  const int*   labels     = (const int*)d_in[1];
  const int*   act_lens   = (const int*)d_in[2];
  const int*   label_lens = (const int*)d_in[3];

  float* lpb   = (float*)d_ws;                       // B*T*PAD floats
  float* lpl   = lpb + (size_t)B_ * WS_PER_;         // B*T*PAD floats
  float* costs = lpl + (size_t)B_ * WS_PER_;         // B floats
  int*   cnt   = (int*)(costs + B_);                 // 1 int

  k1_logsoftmax<<<ROWS_ / 4, 256, 0, stream>>>(acts, labels, label_lens, lpb, lpl, cnt);
  k2_alpha<<<B_, 256, 0, stream>>>(lpb, lpl, act_lens, label_lens, costs, cnt, (float*)d_out);
}